// Round 12
// baseline (36.767 us; speedup 1.0000x reference)
//
#include <hip/hip_runtime.h>

// FeatureAttentionLayer: B=32, W=128, K=128, E=256, fp32 — FULLY FUSED.
//   L[i][e] = sum_w x[b][w][i]*lin_w[e][w] + lin_b[e]
//   R[j][e] = sum_w x[b][w][j]*lin_w[e][128+w]
//   e[i][j] = 0.6(dL[i]+dR[j]) + sum_e 0.4a[e]|L+R| + bias   (LReLU identity)
//   att = softmax_j; out[b][w][i] = sigmoid(sum_j att[i][j]*x[b][w][j])
//
// Round-12: six K1 variants (incl. MFMA) all ~27-30us -> the cost is the
// shared inter-kernel structure (P round-trip through global + relaunch +
// cold-L2 refetch), not any inner loop. Fuse everything: per (b,it) block,
// stage x[b] once as bf16 xT (r11-verified layout; doubles as phase-2 x),
// then per 64-e chunk: stage lin_w chunk bf16 -> MFMA-produce R_chunk f32
// (LDS, stride 132) + Lt slice (+lin_b) -> run K2's verified e-loop on it.
// No workspace at all. LDS ~128KB, 1 block/CU (= current K2 occupancy).

typedef float v2f __attribute__((ext_vector_type(2)));
typedef float v4f __attribute__((ext_vector_type(4)));
typedef short bf16x8 __attribute__((ext_vector_type(8)));

__device__ __forceinline__ unsigned pack_bf16x2(float a, float b) {
    unsigned ua = __builtin_bit_cast(unsigned, a);
    unsigned ub = __builtin_bit_cast(unsigned, b);
    ua = (ua + 0x7FFFu + ((ua >> 16) & 1u)) >> 16;   // RNE f32->bf16
    ub = (ub + 0x7FFFu + ((ub >> 16) & 1u)) >> 16;
    return ua | (ub << 16);
}
__device__ __forceinline__ float bf2f(unsigned h) {
    unsigned u = h << 16;
    return __builtin_bit_cast(float, u);
}

// grid (32 b, 8 it), 256 thr (4 waves).
__global__ __launch_bounds__(256) void k_fused(
    const float* __restrict__ x, const float* __restrict__ lin_w,
    const float* __restrict__ lin_b, const float* __restrict__ a,
    const float* __restrict__ bias, float* __restrict__ out)
{
    __shared__ unsigned short xT[128 * 136];   // bf16 x[b] transposed+swizzled (34 KB)
    __shared__ unsigned short As2[64 * 264];   // bf16 lin_w chunk rows (33 KB)
    __shared__ float Rs[64 * 132];             // f32 R chunk [e][j], stride 132 (33.8 KB)
    __shared__ float Lt[256 * 18];             // f32 L^T (+lin_b) [e][i], stride 18 (18 KB)
    __shared__ float att[16 * 132];            // (8.4 KB)
    __shared__ float as6[256], as4[256];       // 0.6a / 0.4a (2 KB)

    const int t = threadIdx.x;
    const int b = blockIdx.x, it = blockIdx.y;

    // ---- stage xT[k][w'] = bf16(x[b][w][k]), col-group swizzle g ^= (k>>3)&15 ----
    {
        const float* xg = x + b * 16384;
        #pragma unroll
        for (int q = 0; q < 8; ++q) {
            const int idx = t + q * 256;                 // 0..2047
            const int wp = idx >> 5;                     // w-pair 0..63
            const int k4 = (idx & 31) << 2;
            const v4f r0 = *(const v4f*)(xg + (2 * wp) * 128 + k4);
            const v4f r1 = *(const v4f*)(xg + (2 * wp + 1) * 128 + k4);
            const int g   = wp >> 2;
            const int off = (2 * wp) & 7;
            #pragma unroll
            for (int u = 0; u < 4; ++u) {
                const int k = k4 + u;
                const int gs = g ^ ((k >> 3) & 15);
                *(unsigned*)&xT[k * 136 + (gs << 3) + off] = pack_bf16x2(r0[u], r1[u]);
            }
        }
    }
    as6[t] = 0.6f * a[t];
    as4[t] = 0.4f * a[t];

    const int l = t & 63, wave = t >> 6;
    const int lr = l & 15, lg = l >> 4;
    const int jp = t & 31, iq = t >> 5;
    const int j0 = jp * 4, il0 = iq * 2;

    float acc0[4] = {}, acc1[4] = {};      // sum 0.4a*|L+R| per jj, rows il0/il0+1
    float dr[4] = {};                      // sum 0.6a*R per jj
    float dl0 = 0.f, dl1 = 0.f;            // sum 0.6a*L per row

    #pragma unroll 1
    for (int c = 0; c < 4; ++c) {
        // ---- stage As2[rr][0:256] = bf16(lin_w[c*64+rr][0:256]) ----
        #pragma unroll
        for (int q = 0; q < 32; ++q) {
            const int idx = t + q * 256;               // 0..8191
            const int rr = idx >> 7, cp = idx & 127;
            const v2f wv = *(const v2f*)(lin_w + (size_t)(c * 64 + rr) * 256 + 2 * cp);
            *(unsigned*)&As2[rr * 264 + 2 * cp] = pack_bf16x2(wv.x, wv.y);
        }
        __syncthreads();

        // ---- MFMA: produce R chunk (16e x 128j per wave) + Lt slice (16e x 16i) ----
        {
            bf16x8 afL[4], afR[4];
            #pragma unroll
            for (int kc = 0; kc < 4; ++kc) {
                afL[kc] = *(const bf16x8*)&As2[(wave * 16 + lr) * 264 + kc * 32 + lg * 8];
                afR[kc] = *(const bf16x8*)&As2[(wave * 16 + lr) * 264 + 128 + kc * 32 + lg * 8];
            }
            // L: B rows are i = it*16 + lr
            v4f accL = (v4f){0.f, 0.f, 0.f, 0.f};
            {
                const int row = it * 16 + lr;
                const int vr = (row >> 3) & 15;
                #pragma unroll
                for (int kc = 0; kc < 4; ++kc) {
                    const bf16x8 bfv = *(const bf16x8*)&xT[row * 136 + (((kc * 4 + lg) ^ vr) << 3)];
                    accL = __builtin_amdgcn_mfma_f32_16x16x32_bf16(afL[kc], bfv, accL, 0, 0, 0);
                }
            }
            // R: B rows are j = nf*16 + lr
            v4f accR[8];
            #pragma unroll
            for (int nf = 0; nf < 8; ++nf) accR[nf] = (v4f){0.f, 0.f, 0.f, 0.f};
            #pragma unroll
            for (int nf = 0; nf < 8; ++nf) {
                const int row = nf * 16 + lr;
                const int vr = (row >> 3) & 15;
                #pragma unroll
                for (int kc = 0; kc < 4; ++kc) {
                    const bf16x8 bfv = *(const bf16x8*)&xT[row * 136 + (((kc * 4 + lg) ^ vr) << 3)];
                    accR[nf] = __builtin_amdgcn_mfma_f32_16x16x32_bf16(afR[kc], bfv, accR[nf], 0, 0, 0);
                }
            }
            // write: D row m = wave*16 + lg*4 + j, col n = base + lr (r11-verified)
            const int el = wave * 16 + lg * 4;
            #pragma unroll
            for (int j = 0; j < 4; ++j) {
                Lt[(c * 64 + el + j) * 18 + lr] = accL[j] + lin_b[c * 64 + el + j];
                #pragma unroll
                for (int nf = 0; nf < 8; ++nf)
                    Rs[(el + j) * 132 + nf * 16 + lr] = accR[nf][j];
            }
        }
        __syncthreads();

        // ---- e-loop on this chunk (K2-verified, strides 132/18) ----
        const int eg0 = c * 64;
        #pragma unroll
        for (int g = 0; g < 16; ++g) {
            const int e0 = g * 4, eg = eg0 + e0;
            v4f rv[4]; float2 lv[4];
            #pragma unroll
            for (int u = 0; u < 4; ++u) {
                rv[u] = *(const v4f*)&Rs[(e0 + u) * 132 + j0];
                lv[u] = *(const float2*)&Lt[(eg + u) * 18 + il0];
            }
            const v4f a6v = *(const v4f*)&as6[eg];
            const v4f a4v = *(const v4f*)&as4[eg];
            #pragma unroll
            for (int u = 0; u < 4; ++u) {
                const float a6u = a6v[u], a4u = a4v[u];
                const float l0 = lv[u].x, l1 = lv[u].y;
                dl0 = fmaf(a6u, l0, dl0);
                dl1 = fmaf(a6u, l1, dl1);
                #pragma unroll
                for (int jj = 0; jj < 4; ++jj) {
                    const float r = rv[u][jj];
                    dr[jj]   = fmaf(a6u, r, dr[jj]);
                    acc0[jj] = fmaf(a4u, fabsf(l0 + r), acc0[jj]);
                    acc1[jj] = fmaf(a4u, fabsf(l1 + r), acc1[jj]);
                }
            }
        }
        __syncthreads();
    }

    // ---- softmax over j (row lives in one 32-lane half-wave) ----
    const int i0r = it * 16 + il0;
    float ev0[4], ev1[4];
    {
        const v4f b0 = *(const v4f*)(bias + (i0r + 0) * 128 + j0);
        const v4f b1 = *(const v4f*)(bias + (i0r + 1) * 128 + j0);
        #pragma unroll
        for (int jj = 0; jj < 4; ++jj) {
            ev0[jj] = acc0[jj] + dl0 + dr[jj] + b0[jj];
            ev1[jj] = acc1[jj] + dl1 + dr[jj] + b1[jj];
        }
    }
#define SOFTMAX_ROW(EV, ROW) do {                                               \
    float m_ = fmaxf(fmaxf(EV[0], EV[1]), fmaxf(EV[2], EV[3]));                 \
    _Pragma("unroll") for (int d_ = 1; d_ <= 16; d_ <<= 1)                      \
        m_ = fmaxf(m_, __shfl_xor(m_, d_));                                     \
    float p0 = __expf(EV[0] - m_), p1 = __expf(EV[1] - m_);                     \
    float p2 = __expf(EV[2] - m_), p3 = __expf(EV[3] - m_);                     \
    float s_ = p0 + p1 + p2 + p3;                                               \
    _Pragma("unroll") for (int d_ = 1; d_ <= 16; d_ <<= 1)                      \
        s_ += __shfl_xor(s_, d_);                                               \
    const float inv_ = 1.f / s_;                                                \
    *(v4f*)&att[(ROW) * 132 + j0] =                                             \
        (v4f){p0 * inv_, p1 * inv_, p2 * inv_, p3 * inv_}; } while (0)

    SOFTMAX_ROW(ev0, il0 + 0);
    SOFTMAX_ROW(ev1, il0 + 1);
    __syncthreads();

    // ---- phase 2: out[b][w][i] = sigmoid(sum_j att[i][j]*x[b][w][j]) ----
    // x read from bf16 xT (same swizzled layout; pair (w0, w0+1) in one uint).
    const int iq2 = t & 3, wp = t >> 2;
    const int i4 = iq2 * 4, w0 = wp * 2;
    const int g2 = w0 >> 3, off2 = w0 & 7;
    float o[2][4] = {};
    #pragma unroll 4
    for (int jc = 0; jc < 32; ++jc) {
        v4f av[4];
        #pragma unroll
        for (int q = 0; q < 4; ++q)
            av[q] = *(const v4f*)&att[(i4 + q) * 132 + jc * 4];
        float xv0[4], xv1[4];
        #pragma unroll
        for (int u = 0; u < 4; ++u) {
            const int k = jc * 4 + u;
            const int gs = g2 ^ ((k >> 3) & 15);
            const unsigned pp = *(const unsigned*)&xT[k * 136 + (gs << 3) + off2];
            xv0[u] = bf2f(pp & 0xFFFFu);
            xv1[u] = bf2f(pp >> 16);
        }
        #pragma unroll
        for (int u = 0; u < 4; ++u)
            #pragma unroll
            for (int q = 0; q < 4; ++q) {
                o[0][q] = fmaf(xv0[u], av[q][u], o[0][q]);
                o[1][q] = fmaf(xv1[u], av[q][u], o[1][q]);
            }
    }
    #pragma unroll
    for (int w = 0; w < 2; ++w) {
        v4f r;
        r[0] = 1.f / (1.f + __expf(-o[w][0]));
        r[1] = 1.f / (1.f + __expf(-o[w][1]));
        r[2] = 1.f / (1.f + __expf(-o[w][2]));
        r[3] = 1.f / (1.f + __expf(-o[w][3]));
        *(v4f*)(out + (size_t)b * 16384 + (w0 + w) * 128 + it * 16 + i4) = r;
    }
}

extern "C" void kernel_launch(void* const* d_in, const int* in_sizes, int n_in,
                              void* d_out, int out_size, void* d_ws, size_t ws_size,
                              hipStream_t stream) {
    const float* x     = (const float*)d_in[0];
    const float* lin_w = (const float*)d_in[1];
    const float* lin_b = (const float*)d_in[2];
    const float* a     = (const float*)d_in[3];
    const float* bias  = (const float*)d_in[4];
    float* out = (float*)d_out;
    (void)d_ws; (void)ws_size;

    k_fused<<<dim3(32, 8), 256, 0, stream>>>(x, lin_w, lin_b, a, bias, out);
}